// Round 5
// baseline (445.024 us; speedup 1.0000x reference)
//
#include <hip/hip_runtime.h>
#include <hip/hip_bf16.h>
#include <cstdint>

// Problem constants
#define NB    524288      // batch rows
#define NDIN  32
#define NH    128
#define NLD   16
#define NNE   512

// d_out element offsets (float32 elements)
#define OFF_ZQ   0
#define OFF_SC   8388608
#define OFF_RS   8912896
#define OFF_LOSS 9437184
#define OFF_IDS  9437185

// d_ws float layout
#define WS_LOSS 0
#define WS_W1D  64
#define WS_W1S  (64 + 4096)
#define WS_W1R  (64 + 8192)
#define WS_CBT  (64 + 12288)
#define WS_C2   (64 + 12288 + 8192)

typedef float v2f __attribute__((ext_vector_type(2)));

static __device__ __forceinline__ v2f mk2(float a, float b) { v2f r; r[0] = a; r[1] = b; return r; }
static __device__ __forceinline__ v2f bc2(float s) { return mk2(s, s); }
static __device__ __forceinline__ v2f vfma2(v2f a, v2f b, v2f c) { return __builtin_elementwise_fma(a, b, c); }
static __device__ __forceinline__ v2f vmax0(v2f a) { return __builtin_elementwise_max(a, mk2(0.0f, 0.0f)); }

// ---------------------------------------------------------------------------
// Prep: transpose W1 matrices (32x128 -> 128x32), codebook (16x512 -> 512x16),
// precompute ||c_j||^2 with numpy's pairwise (8-accumulator) order over n=16,
// zero loss accumulator.
// ---------------------------------------------------------------------------
__global__ __launch_bounds__(256) void prep_kernel(
    const float* __restrict__ cb,
    const float* __restrict__ w1d, const float* __restrict__ w1s,
    const float* __restrict__ w1r, float* __restrict__ ws)
{
    int gid = blockIdx.x * 256 + threadIdx.x;
    if (gid == 0) ws[WS_LOSS] = 0.0f;
    if (gid < 4096) {
        int j = gid >> 5, k = gid & 31;           // dest [j][k] <- src [k][j]
        ws[WS_W1D + gid] = w1d[k * NH + j];
        ws[WS_W1S + gid] = w1s[k * NH + j];
        ws[WS_W1R + gid] = w1r[k * NH + j];
    } else if (gid < 4096 + 8192) {
        int idx = gid - 4096;
        int j = idx >> 4, k = idx & 15;           // cbT[j][k] = cb[k][j]
        ws[WS_CBT + idx] = cb[k * NNE + j];
    } else if (gid < 4096 + 8192 + 512) {
        int j = gid - (4096 + 8192);
        float t[16];
#pragma unroll
        for (int k = 0; k < 16; ++k) {
            float c = cb[k * NNE + j];
            t[k] = __fmul_rn(c, c);
        }
        float r8[8];
#pragma unroll
        for (int m = 0; m < 8; ++m) r8[m] = __fadd_rn(t[m], t[m + 8]);
        float acc = __fadd_rn(
            __fadd_rn(__fadd_rn(r8[0], r8[1]), __fadd_rn(r8[2], r8[3])),
            __fadd_rn(__fadd_rn(r8[4], r8[5]), __fadd_rn(r8[6], r8[7])));
        ws[WS_C2 + j] = acc;
    }
}

// ---------------------------------------------------------------------------
// Main: one thread per FOUR rows, as two independent v2f pairs (A: rows
// 4i,4i+1; B: rows 4i+2,4i+3). Every uniform weight/codebook s_load feeds
// 4 FMAs, and the two pairs give in-thread ILP to hide SMEM latency.
// Per-row accumulation order is bit-identical to the round-2/4 passing
// kernels (each row occupies one half of one pair; sequential-k preserved).
// ---------------------------------------------------------------------------
__global__ __launch_bounds__(256, 2) void main_kernel(
    const float* __restrict__ z,
    const float* __restrict__ b1d, const float* __restrict__ w2d, const float* __restrict__ b2d,
    const float* __restrict__ b1s, const float* __restrict__ w2s, const float* __restrict__ b2s,
    const float* __restrict__ b1r, const float* __restrict__ w2r, const float* __restrict__ b2r,
    const float* __restrict__ ws,
    float* __restrict__ loss_acc,
    float* __restrict__ out)
{
#pragma clang fp contract(off)
    const int i  = blockIdx.x * 256 + threadIdx.x;   // quad index
    const int r0 = 4 * i;                            // rows r0 .. r0+3

    const float* __restrict__ w1dT = ws + WS_W1D;
    const float* __restrict__ w1sT = ws + WS_W1S;
    const float* __restrict__ w1rT = ws + WS_W1R;
    const float* __restrict__ cbT  = ws + WS_CBT;
    const float* __restrict__ c2   = ws + WS_C2;

    // load 4 rows (4 x 32 floats), pack across rows into two v2f pairs
    v2f xa[32], xb[32];
    {
        const float4* zv = reinterpret_cast<const float4*>(z) + (size_t)r0 * 8;
#pragma unroll
        for (int m = 0; m < 8; ++m) {
            float4 a0 = zv[m];        // row r0
            float4 a1 = zv[m + 8];    // row r0+1
            float4 b0 = zv[m + 16];   // row r0+2
            float4 b1 = zv[m + 24];   // row r0+3
            xa[4*m+0] = mk2(a0.x, a1.x); xa[4*m+1] = mk2(a0.y, a1.y);
            xa[4*m+2] = mk2(a0.z, a1.z); xa[4*m+3] = mk2(a0.w, a1.w);
            xb[4*m+0] = mk2(b0.x, b1.x); xb[4*m+1] = mk2(b0.y, b1.y);
            xb[4*m+2] = mk2(b0.z, b1.z); xb[4*m+3] = mk2(b0.w, b1.w);
        }
    }

    v2f zda[16], zdb[16];
#pragma unroll
    for (int l = 0; l < 16; ++l) { zda[l] = mk2(0.0f, 0.0f); zdb[l] = mk2(0.0f, 0.0f); }
    v2f sacca = mk2(0.0f, 0.0f), racca = mk2(0.0f, 0.0f);
    v2f saccb = mk2(0.0f, 0.0f), raccb = mk2(0.0f, 0.0f);

    for (int j = 0; j < NH; ++j) {
        v2f hda = mk2(0.0f, 0.0f), hsa = mk2(0.0f, 0.0f), hra = mk2(0.0f, 0.0f);
        v2f hdb = mk2(0.0f, 0.0f), hsb = mk2(0.0f, 0.0f), hrb = mk2(0.0f, 0.0f);
        const float* wd  = w1dT + j * 32;
        const float* wsr = w1sT + j * 32;
        const float* wr  = w1rT + j * 32;
#pragma unroll
        for (int k = 0; k < 32; ++k) {
            v2f wdk = bc2(wd[k]), wsk = bc2(wsr[k]), wrk = bc2(wr[k]);
            hda = vfma2(xa[k], wdk, hda);  hdb = vfma2(xb[k], wdk, hdb);
            hsa = vfma2(xa[k], wsk, hsa);  hsb = vfma2(xb[k], wsk, hsb);
            hra = vfma2(xa[k], wrk, hra);  hrb = vfma2(xb[k], wrk, hrb);
        }
        {
            v2f bd = bc2(b1d[j]), bs = bc2(b1s[j]), br = bc2(b1r[j]);
            hda = vmax0(hda + bd);  hdb = vmax0(hdb + bd);
            hsa = vmax0(hsa + bs);  hsb = vmax0(hsb + bs);
            hra = vmax0(hra + br);  hrb = vmax0(hrb + br);
        }
        const float* w2row = w2d + j * 16;
#pragma unroll
        for (int l = 0; l < 16; ++l) {
            v2f w2l = bc2(w2row[l]);
            zda[l] = vfma2(hda, w2l, zda[l]);
            zdb[l] = vfma2(hdb, w2l, zdb[l]);
        }
        {
            v2f wsj = bc2(w2s[j]), wrj = bc2(w2r[j]);
            sacca = vfma2(hsa, wsj, sacca);  saccb = vfma2(hsb, wsj, saccb);
            racca = vfma2(hra, wrj, racca);  raccb = vfma2(hrb, wrj, raccb);
        }
    }
#pragma unroll
    for (int l = 0; l < 16; ++l) {
        v2f b2l = bc2(b2d[l]);
        zda[l] = zda[l] + b2l;
        zdb[l] = zdb[l] + b2l;
    }

    v2f scalera   = sacca + bc2(b2s[0]);
    v2f scalerb   = saccb + bc2(b2s[0]);
    v2f redshifta = vmax0(racca + bc2(b2r[0]));
    v2f redshiftb = vmax0(raccb + bc2(b2r[0]));

    // s = sum(zf*zf): numpy pairwise (8 accumulators + tree), per-row exact
    v2f sa, sb;
    {
        v2f r0v = (zda[0]*zda[0]) + (zda[8]*zda[8]);
        v2f r1v = (zda[1]*zda[1]) + (zda[9]*zda[9]);
        v2f r2v = (zda[2]*zda[2]) + (zda[10]*zda[10]);
        v2f r3v = (zda[3]*zda[3]) + (zda[11]*zda[11]);
        v2f r4v = (zda[4]*zda[4]) + (zda[12]*zda[12]);
        v2f r5v = (zda[5]*zda[5]) + (zda[13]*zda[13]);
        v2f r6v = (zda[6]*zda[6]) + (zda[14]*zda[14]);
        v2f r7v = (zda[7]*zda[7]) + (zda[15]*zda[15]);
        sa = ((r0v + r1v) + (r2v + r3v)) + ((r4v + r5v) + (r6v + r7v));
    }
    {
        v2f r0v = (zdb[0]*zdb[0]) + (zdb[8]*zdb[8]);
        v2f r1v = (zdb[1]*zdb[1]) + (zdb[9]*zdb[9]);
        v2f r2v = (zdb[2]*zdb[2]) + (zdb[10]*zdb[10]);
        v2f r3v = (zdb[3]*zdb[3]) + (zdb[11]*zdb[11]);
        v2f r4v = (zdb[4]*zdb[4]) + (zdb[12]*zdb[12]);
        v2f r5v = (zdb[5]*zdb[5]) + (zdb[13]*zdb[13]);
        v2f r6v = (zdb[6]*zdb[6]) + (zdb[14]*zdb[14]);
        v2f r7v = (zdb[7]*zdb[7]) + (zdb[15]*zdb[15]);
        sb = ((r0v + r1v) + (r2v + r3v)) + ((r4v + r5v) + (r6v + r7v));
    }

    // VQ argmin over 512 entries; codebook row broadcast feeds all 4 rows
    float best0 = 3.4028235e38f, best1 = 3.4028235e38f;
    float best2 = 3.4028235e38f, best3 = 3.4028235e38f;
    int bid0 = 0, bid1 = 0, bid2 = 0, bid3 = 0;
#pragma unroll 2
    for (int j = 0; j < NNE; ++j) {
        const float* cj = cbT + j * 16;
        v2f ba = zda[0] * bc2(cj[0]);
        v2f bb = zdb[0] * bc2(cj[0]);
#pragma unroll
        for (int k = 1; k < 16; ++k) {
            v2f cjk = bc2(cj[k]);
            ba = vfma2(zda[k], cjk, ba);
            bb = vfma2(zdb[k], cjk, bb);
        }
        v2f c2j = bc2(c2[j]);
        v2f dja = (sa - (ba + ba)) + c2j;   // b+b == 2*b exactly
        v2f djb = (sb - (bb + bb)) + c2j;
        float d0 = dja[0], d1 = dja[1], d2 = djb[0], d3 = djb[1];
        bool t0 = d0 < best0; best0 = t0 ? d0 : best0; bid0 = t0 ? j : bid0;
        bool t1 = d1 < best1; best1 = t1 ? d1 : best1; bid1 = t1 ? j : bid1;
        bool t2 = d2 < best2; best2 = t2 ? d2 : best2; bid2 = t2 ? j : bid2;
        bool t3 = d3 < best3; best3 = t3 ? d3 : best3; bid3 = t3 ? j : bid3;
    }

    // gather z_q, z_q_st = zd + (q - zd), loss partials, stores
    float lsum = 0.0f;
    float4* ozq = reinterpret_cast<float4*>(out) + (size_t)r0 * 4;
    const int   bids[4] = { bid0, bid1, bid2, bid3 };
#pragma unroll
    for (int rr = 0; rr < 4; ++rr) {
        const float4* cq = reinterpret_cast<const float4*>(cbT + bids[rr] * 16);
        const v2f* zdp = (rr < 2) ? zda : zdb;
        const int h = rr & 1;
#pragma unroll
        for (int m = 0; m < 4; ++m) {
            float4 q = cq[m];
            float z0v = zdp[4*m+0][h], z1v = zdp[4*m+1][h];
            float z2v = zdp[4*m+2][h], z3v = zdp[4*m+3][h];
            float e0 = __fsub_rn(q.x, z0v), e1 = __fsub_rn(q.y, z1v);
            float e2 = __fsub_rn(q.z, z2v), e3 = __fsub_rn(q.w, z3v);
            lsum = __fmaf_rn(e0, e0, lsum); lsum = __fmaf_rn(e1, e1, lsum);
            lsum = __fmaf_rn(e2, e2, lsum); lsum = __fmaf_rn(e3, e3, lsum);
            ozq[rr * 4 + m] = make_float4(__fadd_rn(z0v, e0), __fadd_rn(z1v, e1),
                                          __fadd_rn(z2v, e2), __fadd_rn(z3v, e3));
        }
    }

    *reinterpret_cast<float4*>(out + OFF_SC + r0) =
        make_float4(scalera[0], scalera[1], scalerb[0], scalerb[1]);
    *reinterpret_cast<float4*>(out + OFF_RS + r0) =
        make_float4(redshifta[0], redshifta[1], redshiftb[0], redshiftb[1]);
    *reinterpret_cast<float4*>(out + OFF_IDS + r0) =
        make_float4((float)bid0, (float)bid1, (float)bid2, (float)bid3);

    // loss reduction: wave shuffle -> LDS -> one atomic per block
#pragma unroll
    for (int off = 32; off > 0; off >>= 1) lsum += __shfl_down(lsum, off);
    __shared__ float red[4];
    if ((threadIdx.x & 63) == 0) red[threadIdx.x >> 6] = lsum;
    __syncthreads();
    if (threadIdx.x == 0)
        atomicAdd(loss_acc, red[0] + red[1] + red[2] + red[3]);
}

__global__ void fin_kernel(const float* __restrict__ ws, float* __restrict__ out) {
    float m = ws[WS_LOSS] / 8388608.0f;   // mean over B*LD
    out[OFF_LOSS] = m + 0.25f * m;        // (1 + BETA) * mean
}

extern "C" void kernel_launch(void* const* d_in, const int* in_sizes, int n_in,
                              void* d_out, int out_size, void* d_ws, size_t ws_size,
                              hipStream_t stream)
{
    const float* z      = (const float*)d_in[0];
    const float* cb     = (const float*)d_in[1];
    const float* dec_w1 = (const float*)d_in[2];
    const float* dec_b1 = (const float*)d_in[3];
    const float* dec_w2 = (const float*)d_in[4];
    const float* dec_b2 = (const float*)d_in[5];
    const float* sc_w1  = (const float*)d_in[6];
    const float* sc_b1  = (const float*)d_in[7];
    const float* sc_w2  = (const float*)d_in[8];
    const float* sc_b2  = (const float*)d_in[9];
    const float* rs_w1  = (const float*)d_in[10];
    const float* rs_b1  = (const float*)d_in[11];
    const float* rs_w2  = (const float*)d_in[12];
    const float* rs_b2  = (const float*)d_in[13];

    float* ws = (float*)d_ws;
    float* out = (float*)d_out;

    prep_kernel<<<50, 256, 0, stream>>>(cb, dec_w1, sc_w1, rs_w1, ws);
    main_kernel<<<NB / 4 / 256, 256, 0, stream>>>(
        z,
        dec_b1, dec_w2, dec_b2,
        sc_b1,  sc_w2,  sc_b2,
        rs_b1,  rs_w2,  rs_b2,
        ws, ws + WS_LOSS, out);
    fin_kernel<<<1, 1, 0, stream>>>(ws, out);
}

// Round 6
// 416.955 us; speedup vs baseline: 1.0673x; 1.0673x over previous
//
#include <hip/hip_runtime.h>
#include <hip/hip_bf16.h>
#include <cstdint>

// Problem constants
#define NB    524288      // batch rows
#define NDIN  32
#define NH    128
#define NLD   16
#define NNE   512

// d_out element offsets (float32 elements)
#define OFF_ZQ   0
#define OFF_SC   8388608
#define OFF_RS   8912896
#define OFF_LOSS 9437184
#define OFF_IDS  9437185

// d_ws float layout
#define WS_LOSS 0
#define WS_W1D  64
#define WS_W1S  (64 + 4096)
#define WS_W1R  (64 + 8192)
#define WS_CBT  (64 + 12288)
#define WS_C2   (64 + 12288 + 8192)

typedef float v2f __attribute__((ext_vector_type(2)));

static __device__ __forceinline__ v2f mk2(float a, float b) { v2f r; r[0] = a; r[1] = b; return r; }
static __device__ __forceinline__ v2f bc2(float s) { return mk2(s, s); }
static __device__ __forceinline__ v2f vfma2(v2f a, v2f b, v2f c) { return __builtin_elementwise_fma(a, b, c); }
static __device__ __forceinline__ v2f vmax0(v2f a) { return __builtin_elementwise_max(a, mk2(0.0f, 0.0f)); }

// ---------------------------------------------------------------------------
// Prep: transpose W1 matrices (32x128 -> 128x32), codebook (16x512 -> 512x16),
// precompute ||c_j||^2 with numpy's pairwise (8-accumulator) order over n=16,
// zero loss accumulator.
// ---------------------------------------------------------------------------
__global__ __launch_bounds__(256) void prep_kernel(
    const float* __restrict__ cb,
    const float* __restrict__ w1d, const float* __restrict__ w1s,
    const float* __restrict__ w1r, float* __restrict__ ws)
{
    int gid = blockIdx.x * 256 + threadIdx.x;
    if (gid == 0) ws[WS_LOSS] = 0.0f;
    if (gid < 4096) {
        int j = gid >> 5, k = gid & 31;           // dest [j][k] <- src [k][j]
        ws[WS_W1D + gid] = w1d[k * NH + j];
        ws[WS_W1S + gid] = w1s[k * NH + j];
        ws[WS_W1R + gid] = w1r[k * NH + j];
    } else if (gid < 4096 + 8192) {
        int idx = gid - 4096;
        int j = idx >> 4, k = idx & 15;           // cbT[j][k] = cb[k][j]
        ws[WS_CBT + idx] = cb[k * NNE + j];
    } else if (gid < 4096 + 8192 + 512) {
        int j = gid - (4096 + 8192);
        float t[16];
#pragma unroll
        for (int k = 0; k < 16; ++k) {
            float c = cb[k * NNE + j];
            t[k] = __fmul_rn(c, c);
        }
        float r8[8];
#pragma unroll
        for (int m = 0; m < 8; ++m) r8[m] = __fadd_rn(t[m], t[m + 8]);
        float acc = __fadd_rn(
            __fadd_rn(__fadd_rn(r8[0], r8[1]), __fadd_rn(r8[2], r8[3])),
            __fadd_rn(__fadd_rn(r8[4], r8[5]), __fadd_rn(r8[6], r8[7])));
        ws[WS_C2 + j] = acc;
    }
}

// ---------------------------------------------------------------------------
// K1 (MLP): round-4's proven 2-row packed j-loop, minus VQ. Writes zd into
// the z_q output region (fp32 roundtrip is bit-exact; K2 overwrites it),
// plus scaler/redshift. Weights via wave-uniform s_load as before.
// ---------------------------------------------------------------------------
__global__ __launch_bounds__(256, 4) void mlp_kernel(
    const float* __restrict__ z,
    const float* __restrict__ b1d, const float* __restrict__ w2d, const float* __restrict__ b2d,
    const float* __restrict__ b1s, const float* __restrict__ w2s, const float* __restrict__ b2s,
    const float* __restrict__ b1r, const float* __restrict__ w2r, const float* __restrict__ b2r,
    const float* __restrict__ ws,
    float* __restrict__ out)
{
#pragma clang fp contract(off)
    const int i  = blockIdx.x * 256 + threadIdx.x;   // pair index
    const int r0 = 2 * i;                            // rows r0, r0+1

    const float* __restrict__ w1dT = ws + WS_W1D;
    const float* __restrict__ w1sT = ws + WS_W1S;
    const float* __restrict__ w1rT = ws + WS_W1R;

    // load both rows (2 x 32 floats) and pack across rows
    v2f x2[32];
    {
        const float4* zv = reinterpret_cast<const float4*>(z) + (size_t)r0 * 8;
#pragma unroll
        for (int m = 0; m < 8; ++m) {
            float4 a = zv[m];       // row r0
            float4 b = zv[m + 8];   // row r0+1
            x2[4*m+0] = mk2(a.x, b.x);
            x2[4*m+1] = mk2(a.y, b.y);
            x2[4*m+2] = mk2(a.z, b.z);
            x2[4*m+3] = mk2(a.w, b.w);
        }
    }

    v2f zd2[16];
#pragma unroll
    for (int l = 0; l < 16; ++l) zd2[l] = mk2(0.0f, 0.0f);
    v2f sacc2 = mk2(0.0f, 0.0f), racc2 = mk2(0.0f, 0.0f);

    for (int j = 0; j < NH; ++j) {
        v2f hd2 = mk2(0.0f, 0.0f), hs2 = mk2(0.0f, 0.0f), hr2 = mk2(0.0f, 0.0f);
        const float* wd  = w1dT + j * 32;
        const float* wsr = w1sT + j * 32;
        const float* wr  = w1rT + j * 32;
#pragma unroll
        for (int k = 0; k < 32; ++k) {
            hd2 = vfma2(x2[k], bc2(wd[k]),  hd2);
            hs2 = vfma2(x2[k], bc2(wsr[k]), hs2);
            hr2 = vfma2(x2[k], bc2(wr[k]),  hr2);
        }
        hd2 = vmax0(hd2 + bc2(b1d[j]));
        hs2 = vmax0(hs2 + bc2(b1s[j]));
        hr2 = vmax0(hr2 + bc2(b1r[j]));
        const float* w2row = w2d + j * 16;
#pragma unroll
        for (int l = 0; l < 16; ++l) zd2[l] = vfma2(hd2, bc2(w2row[l]), zd2[l]);
        sacc2 = vfma2(hs2, bc2(w2s[j]), sacc2);
        racc2 = vfma2(hr2, bc2(w2r[j]), racc2);
    }
#pragma unroll
    for (int l = 0; l < 16; ++l) zd2[l] = zd2[l] + bc2(b2d[l]);

    v2f scaler2   = sacc2 + bc2(b2s[0]);
    v2f redshift2 = vmax0(racc2 + bc2(b2r[0]));

    // write zd (both rows) into the z_q region; K2 consumes and overwrites
    float4* ozq = reinterpret_cast<float4*>(out) + (size_t)r0 * 4;
#pragma unroll
    for (int m = 0; m < 4; ++m) {
        ozq[m]     = make_float4(zd2[4*m+0][0], zd2[4*m+1][0], zd2[4*m+2][0], zd2[4*m+3][0]);
        ozq[4 + m] = make_float4(zd2[4*m+0][1], zd2[4*m+1][1], zd2[4*m+2][1], zd2[4*m+3][1]);
    }

    *reinterpret_cast<float2*>(out + OFF_SC + r0) = make_float2(scaler2[0],   scaler2[1]);
    *reinterpret_cast<float2*>(out + OFF_RS + r0) = make_float2(redshift2[0], redshift2[1]);
}

// ---------------------------------------------------------------------------
// K2 (VQ): codebook + ||c||^2 staged in LDS (34 KB), 512-thread blocks,
// 2 rows/thread. Reads zd from the z_q region, computes argmin with the
// exact r2/r4 op order, overwrites z_q_st in place, writes ids and the
// loss partial. Uniform ds_read broadcasts replace the s_load stream.
// ---------------------------------------------------------------------------
__global__ __launch_bounds__(512, 4) void vq_kernel(
    const float* __restrict__ ws,
    float* __restrict__ loss_acc,
    float* __restrict__ out)
{
#pragma clang fp contract(off)
    __shared__ float lcb[NNE * 16];   // 32 KB
    __shared__ float lc2[NNE];        //  2 KB
    __shared__ float red[8];

    const int t = threadIdx.x;
    {
        const float* __restrict__ cbT = ws + WS_CBT;
        const float* __restrict__ c2  = ws + WS_C2;
#pragma unroll
        for (int m = 0; m < 16; ++m) lcb[t + m * 512] = cbT[t + m * 512];
        lc2[t & 511] = c2[t & 511];
    }
    __syncthreads();

    const int i  = blockIdx.x * 512 + t;   // pair index
    const int r0 = 2 * i;

    // load zd (2 rows x 16 floats) from the z_q region, pack across rows
    v2f zd2[16];
    float4* ozq = reinterpret_cast<float4*>(out) + (size_t)r0 * 4;
#pragma unroll
    for (int m = 0; m < 4; ++m) {
        float4 a = ozq[m];
        float4 b = ozq[4 + m];
        zd2[4*m+0] = mk2(a.x, b.x);
        zd2[4*m+1] = mk2(a.y, b.y);
        zd2[4*m+2] = mk2(a.z, b.z);
        zd2[4*m+3] = mk2(a.w, b.w);
    }

    // s = sum(zf*zf): numpy pairwise (8 accumulators + tree), per-row exact
    v2f s2;
    {
        v2f r0v = (zd2[0]*zd2[0]) + (zd2[8]*zd2[8]);
        v2f r1v = (zd2[1]*zd2[1]) + (zd2[9]*zd2[9]);
        v2f r2v = (zd2[2]*zd2[2]) + (zd2[10]*zd2[10]);
        v2f r3v = (zd2[3]*zd2[3]) + (zd2[11]*zd2[11]);
        v2f r4v = (zd2[4]*zd2[4]) + (zd2[12]*zd2[12]);
        v2f r5v = (zd2[5]*zd2[5]) + (zd2[13]*zd2[13]);
        v2f r6v = (zd2[6]*zd2[6]) + (zd2[14]*zd2[14]);
        v2f r7v = (zd2[7]*zd2[7]) + (zd2[15]*zd2[15]);
        s2 = ((r0v + r1v) + (r2v + r3v)) + ((r4v + r5v) + (r6v + r7v));
    }

    // VQ argmin over 512 entries from LDS; first-index tie-break (strict <)
    float best0 = 3.4028235e38f, best1 = 3.4028235e38f;
    int bid0 = 0, bid1 = 0;
#pragma unroll 2
    for (int j = 0; j < NNE; ++j) {
        const float* cj = lcb + j * 16;
        v2f b2 = zd2[0] * bc2(cj[0]);
#pragma unroll
        for (int k = 1; k < 16; ++k) b2 = vfma2(zd2[k], bc2(cj[k]), b2);
        v2f dj2 = (s2 - (b2 + b2)) + bc2(lc2[j]);   // b+b == 2*b exactly
        float d0 = dj2[0], d1 = dj2[1];
        bool t0 = d0 < best0; best0 = t0 ? d0 : best0; bid0 = t0 ? j : bid0;
        bool t1 = d1 < best1; best1 = t1 ? d1 : best1; bid1 = t1 ? j : bid1;
    }

    // gather z_q from LDS, z_q_st = zd + (q - zd), loss partials, stores
    float lsum = 0.0f;
    {
        const float* cq = lcb + bid0 * 16;
#pragma unroll
        for (int m = 0; m < 4; ++m) {
            float q0 = cq[4*m+0], q1 = cq[4*m+1], q2 = cq[4*m+2], q3 = cq[4*m+3];
            float z0v = zd2[4*m+0][0], z1v = zd2[4*m+1][0], z2v = zd2[4*m+2][0], z3v = zd2[4*m+3][0];
            float e0 = __fsub_rn(q0, z0v), e1 = __fsub_rn(q1, z1v);
            float e2 = __fsub_rn(q2, z2v), e3 = __fsub_rn(q3, z3v);
            lsum = __fmaf_rn(e0, e0, lsum); lsum = __fmaf_rn(e1, e1, lsum);
            lsum = __fmaf_rn(e2, e2, lsum); lsum = __fmaf_rn(e3, e3, lsum);
            ozq[m] = make_float4(__fadd_rn(z0v, e0), __fadd_rn(z1v, e1),
                                 __fadd_rn(z2v, e2), __fadd_rn(z3v, e3));
        }
    }
    {
        const float* cq = lcb + bid1 * 16;
#pragma unroll
        for (int m = 0; m < 4; ++m) {
            float q0 = cq[4*m+0], q1 = cq[4*m+1], q2 = cq[4*m+2], q3 = cq[4*m+3];
            float z0v = zd2[4*m+0][1], z1v = zd2[4*m+1][1], z2v = zd2[4*m+2][1], z3v = zd2[4*m+3][1];
            float e0 = __fsub_rn(q0, z0v), e1 = __fsub_rn(q1, z1v);
            float e2 = __fsub_rn(q2, z2v), e3 = __fsub_rn(q3, z3v);
            lsum = __fmaf_rn(e0, e0, lsum); lsum = __fmaf_rn(e1, e1, lsum);
            lsum = __fmaf_rn(e2, e2, lsum); lsum = __fmaf_rn(e3, e3, lsum);
            ozq[4 + m] = make_float4(__fadd_rn(z0v, e0), __fadd_rn(z1v, e1),
                                     __fadd_rn(z2v, e2), __fadd_rn(z3v, e3));
        }
    }

    *reinterpret_cast<float2*>(out + OFF_IDS + r0) = make_float2((float)bid0, (float)bid1);

    // loss reduction: wave shuffle -> LDS -> one atomic per block
#pragma unroll
    for (int off = 32; off > 0; off >>= 1) lsum += __shfl_down(lsum, off);
    if ((t & 63) == 0) red[t >> 6] = lsum;
    __syncthreads();
    if (t == 0) {
        float acc = 0.0f;
#pragma unroll
        for (int m = 0; m < 8; ++m) acc += red[m];
        atomicAdd(loss_acc, acc);
    }
}

__global__ void fin_kernel(const float* __restrict__ ws, float* __restrict__ out) {
    float m = ws[WS_LOSS] / 8388608.0f;   // mean over B*LD
    out[OFF_LOSS] = m + 0.25f * m;        // (1 + BETA) * mean
}

extern "C" void kernel_launch(void* const* d_in, const int* in_sizes, int n_in,
                              void* d_out, int out_size, void* d_ws, size_t ws_size,
                              hipStream_t stream)
{
    const float* z      = (const float*)d_in[0];
    const float* cb     = (const float*)d_in[1];
    const float* dec_w1 = (const float*)d_in[2];
    const float* dec_b1 = (const float*)d_in[3];
    const float* dec_w2 = (const float*)d_in[4];
    const float* dec_b2 = (const float*)d_in[5];
    const float* sc_w1  = (const float*)d_in[6];
    const float* sc_b1  = (const float*)d_in[7];
    const float* sc_w2  = (const float*)d_in[8];
    const float* sc_b2  = (const float*)d_in[9];
    const float* rs_w1  = (const float*)d_in[10];
    const float* rs_b1  = (const float*)d_in[11];
    const float* rs_w2  = (const float*)d_in[12];
    const float* rs_b2  = (const float*)d_in[13];

    float* ws = (float*)d_ws;
    float* out = (float*)d_out;

    prep_kernel<<<50, 256, 0, stream>>>(cb, dec_w1, sc_w1, rs_w1, ws);
    mlp_kernel<<<NB / 2 / 256, 256, 0, stream>>>(
        z,
        dec_b1, dec_w2, dec_b2,
        sc_b1,  sc_w2,  sc_b2,
        rs_b1,  rs_w2,  rs_b2,
        ws, out);
    vq_kernel<<<NB / 2 / 512, 512, 0, stream>>>(ws, ws + WS_LOSS, out);
    fin_kernel<<<1, 1, 0, stream>>>(ws, out);
}